// Round 1
// baseline (410.103 us; speedup 1.0000x reference)
//
#include <hip/hip_runtime.h>

// y = relu(x @ W1 + b1) @ W2 + b2
// x: [B, 64] fp32, W1: [64, 32], b1: [32], W2: [32, 16], b2: [16], y: [B, 16]
// B = 1048576. Memory-bound: 268 MB read + 67 MB write -> ~53 us floor @ 6.3 TB/s.
// One thread per row. Weights read at wave-uniform addresses -> s_load broadcast
// into SGPRs; FMAs are v_fmac_f32 with the weight as the scalar operand.

#define N_IN  64
#define N_MID 32
#define N_OUT 16

__global__ __launch_bounds__(256) void livenet_mlp_kernel(
    const float* __restrict__ x,
    const float* __restrict__ W1,
    const float* __restrict__ b1,
    const float* __restrict__ W2,
    const float* __restrict__ b2,
    float* __restrict__ y,
    int nrows)
{
    const int row = blockIdx.x * blockDim.x + threadIdx.x;
    if (row >= nrows) return;

    // ---- Load the full 64-float row as 16 float4s (deep MLP for latency hiding).
    const float4* __restrict__ xr =
        reinterpret_cast<const float4*>(x + (size_t)row * N_IN);
    float4 xv[16];
#pragma unroll
    for (int i = 0; i < 16; ++i) xv[i] = xr[i];

    // ---- h = x @ W1 + b1 (accumulate fp32; weights wave-uniform -> SGPR).
    float h[N_MID];
#pragma unroll
    for (int j = 0; j < N_MID; ++j) h[j] = b1[j];

#pragma unroll
    for (int kk = 0; kk < 16; ++kk) {
        const float xs0 = xv[kk].x;
        const float xs1 = xv[kk].y;
        const float xs2 = xv[kk].z;
        const float xs3 = xv[kk].w;
        const int k = kk * 4;
#pragma unroll
        for (int j = 0; j < N_MID; ++j)
            h[j] = __builtin_fmaf(xs0, W1[(k + 0) * N_MID + j], h[j]);
#pragma unroll
        for (int j = 0; j < N_MID; ++j)
            h[j] = __builtin_fmaf(xs1, W1[(k + 1) * N_MID + j], h[j]);
#pragma unroll
        for (int j = 0; j < N_MID; ++j)
            h[j] = __builtin_fmaf(xs2, W1[(k + 2) * N_MID + j], h[j]);
#pragma unroll
        for (int j = 0; j < N_MID; ++j)
            h[j] = __builtin_fmaf(xs3, W1[(k + 3) * N_MID + j], h[j]);
    }

    // ---- ReLU
#pragma unroll
    for (int j = 0; j < N_MID; ++j) h[j] = fmaxf(h[j], 0.0f);

    // ---- y = h @ W2 + b2
    float yv[N_OUT];
#pragma unroll
    for (int o = 0; o < N_OUT; ++o) yv[o] = b2[o];
#pragma unroll
    for (int j = 0; j < N_MID; ++j) {
        const float hj = h[j];
#pragma unroll
        for (int o = 0; o < N_OUT; ++o)
            yv[o] = __builtin_fmaf(hj, W2[j * N_OUT + o], yv[o]);
    }

    // ---- Store 16 floats (64 contiguous bytes per lane) as 4 float4s.
    float4* __restrict__ yr = reinterpret_cast<float4*>(y + (size_t)row * N_OUT);
#pragma unroll
    for (int i = 0; i < 4; ++i)
        yr[i] = make_float4(yv[4 * i + 0], yv[4 * i + 1], yv[4 * i + 2], yv[4 * i + 3]);
}

extern "C" void kernel_launch(void* const* d_in, const int* in_sizes, int n_in,
                              void* d_out, int out_size, void* d_ws, size_t ws_size,
                              hipStream_t stream) {
    const float* x  = (const float*)d_in[0];
    const float* W1 = (const float*)d_in[1];
    const float* b1 = (const float*)d_in[2];
    const float* W2 = (const float*)d_in[3];
    const float* b2 = (const float*)d_in[4];
    float* y = (float*)d_out;

    const int nrows = in_sizes[0] / N_IN;   // 1048576
    const int block = 256;
    const int grid = (nrows + block - 1) / block;  // 4096
    livenet_mlp_kernel<<<grid, block, 0, stream>>>(x, W1, b1, W2, b2, y, nrows);
}